// Round 24
// baseline (135.582 us; speedup 1.0000x reference)
//
#include <hip/hip_runtime.h>

#define N_NODES 50000
#define N_EDGES 1600000
#define IN_DIM 512
#define HID_DIM 128
#define OUT_DIM 16

#define BKT_SHIFT 6
#define BKT_NODES 64
#define NB ((N_NODES + BKT_NODES - 1) / BKT_NODES)   // 782 buckets
#define SC_EDGES 8192
#define SC_BLOCKS ((N_EDGES + SC_EDGES - 1) / SC_EDGES)   // 196 hist/scatter blocks
#define PREP_BLOCKS ((IN_DIM * HID_DIM + 1023) / 1024)    // 64
#define NS_CAP 2560                                  // node_sort LDS stage capacity
#define MG_GEMM_BLOCKS ((N_NODES + 127) / 128)       // 391 gemm1 tiles

typedef __attribute__((ext_vector_type(8))) __bf16 bf16x8;
typedef __attribute__((ext_vector_type(4))) __bf16 bf16x4;
typedef __attribute__((ext_vector_type(8))) unsigned short ushort8;
typedef __attribute__((ext_vector_type(4))) float f32x4;
typedef __attribute__((ext_vector_type(2))) float f32x2;

static __device__ __forceinline__ unsigned short f2bf(float x) {
    unsigned int u = __float_as_uint(x);
    u += 0x7FFFu + ((u >> 16) & 1u);   // round-to-nearest-even
    return (unsigned short)(u >> 16);
}
static __device__ __forceinline__ float bf2f(unsigned short v) {
    return __uint_as_float(((unsigned int)v) << 16);
}
static __device__ __forceinline__ unsigned char f2fp8(float x) {
    int pk = __builtin_amdgcn_cvt_pk_fp8_f32(x, x, 0, false);   // HW e4m3 (gfx950 OCP)
    return (unsigned char)(pk & 0xFF);
}
// async global->LDS DMA, 16B/lane; dest = wave-uniform base + lane*16 (HW rule).
static __device__ __forceinline__ void gload_lds16(const void* g, void* l) {
    __builtin_amdgcn_global_load_lds(
        (const __attribute__((address_space(1))) unsigned int*)g,
        (__attribute__((address_space(3))) unsigned int*)l, 16, 0, 0);
}

__device__ inline int wave_incl_scan(int v) {
    #pragma unroll
    for (int off = 1; off < 64; off <<= 1) {
        int x = __shfl_up(v, off, 64);
        if ((threadIdx.x & 63) >= off) v += x;
    }
    return v;
}

// ================= CSR build =================

__global__ void zero_bcnt_kernel(int* __restrict__ bcnt) {
    int t = threadIdx.x;
    if (t < NB) bcnt[t] = 0;
}

// blocks [0,196): bucket hist (8192 edges, int4-vectorized) + per-block counts to
// blk_hist_T[bucket][block]. blocks [196,260): prep Wt.
__global__ __launch_bounds__(1024) void hist_prep_kernel(const int* __restrict__ dst,
                                                         int* __restrict__ bcnt,
                                                         int* __restrict__ blk_hist_T,
                                                         const float* __restrict__ W1,
                                                         unsigned short* __restrict__ Wt) {
    if (blockIdx.x >= SC_BLOCKS) {
        int i = (blockIdx.x - SC_BLOCKS) * 1024 + threadIdx.x;
        if (i < IN_DIM * HID_DIM) {
            int k = i >> 7, col = i & 127;
            Wt[(size_t)col * IN_DIM + k] = f2bf(W1[i]);
        }
        return;
    }
    __shared__ int lc[NB];
    const int t = threadIdx.x;
    for (int b = t; b < NB; b += 1024) lc[b] = 0;
    __syncthreads();
    const int eb = blockIdx.x * SC_EDGES + t * 8;
    #pragma unroll
    for (int q = 0; q < 2; q++) {
        int e0 = eb + q * 4;
        if (e0 + 4 <= N_EDGES) {
            int4 d4 = *(const int4*)&dst[e0];
            atomicAdd(&lc[d4.x >> BKT_SHIFT], 1);
            atomicAdd(&lc[d4.y >> BKT_SHIFT], 1);
            atomicAdd(&lc[d4.z >> BKT_SHIFT], 1);
            atomicAdd(&lc[d4.w >> BKT_SHIFT], 1);
        } else {
            for (int k = 0; k < 4; k++) {
                int e = e0 + k;
                if (e < N_EDGES) atomicAdd(&lc[dst[e] >> BKT_SHIFT], 1);
            }
        }
    }
    __syncthreads();
    for (int b = t; b < NB; b += 1024) {
        int c = lc[b];
        blk_hist_T[(size_t)b * SC_BLOCKS + blockIdx.x] = c;
        if (c) atomicAdd(&bcnt[b], c);
    }
}

__global__ __launch_bounds__(1024) void bucket_scan_kernel(const int* __restrict__ bcnt,
                                                           int* __restrict__ bucket_ptr) {
    __shared__ int wsums[16];
    const int t = threadIdx.x;
    const int lane = t & 63, wid = t >> 6;
    int v = (t < NB) ? bcnt[t] : 0;
    int incl = wave_incl_scan(v);
    if (lane == 63) wsums[wid] = incl;
    __syncthreads();
    if (wid == 0) {
        int wv = (lane < 16) ? wsums[lane] : 0;
        int ws = wave_incl_scan(wv);
        if (lane < 16) wsums[lane] = ws;
    }
    __syncthreads();
    int woff = wid ? wsums[wid - 1] : 0;
    int excl = woff + incl - v;
    if (t < NB) bucket_ptr[t] = excl;
    if (t == NB - 1) bucket_ptr[NB] = excl + v;
}

// One wave per bucket: in-place exclusive-scan blk_hist_T rows (coalesced).
__global__ __launch_bounds__(512) void base_scan_kernel(const int* __restrict__ bucket_ptr,
                                                        int* __restrict__ blk_hist_T) {
    const int lane = threadIdx.x & 63;
    const int b = blockIdx.x * 8 + (threadIdx.x >> 6);
    if (b >= NB) return;
    int* row = blk_hist_T + (size_t)b * SC_BLOCKS;
    int carry = bucket_ptr[b];
    for (int c0 = 0; c0 < SC_BLOCKS; c0 += 64) {
        int idx = c0 + lane;
        int v = (idx < SC_BLOCKS) ? row[idx] : 0;
        int incl = wave_incl_scan(v);
        if (idx < SC_BLOCKS) row[idx] = carry + incl - v;
        carry += __shfl(incl, 63, 64);
    }
}

// ======= merged: blocks [0,391) gemm1 (global_load_lds staging); [391,587) scatter =======
// X staged as f32 via async DMA (compiler cannot sink it -> loads stay in flight,
// cross-block overlap hides HBM latency). XOR-swizzled source + swizzled ds_read.

__global__ __launch_bounds__(512) void scatter_gemm1_kernel(const float* __restrict__ X,
                                                            const unsigned short* __restrict__ Wt,
                                                            unsigned char* __restrict__ h0,
                                                            const int* __restrict__ src,
                                                            const int* __restrict__ dst,
                                                            const float* __restrict__ val,
                                                            const int* __restrict__ blk_hist_T,
                                                            int2* __restrict__ pairs_bkt) {
    if (blockIdx.x < MG_GEMM_BLOCKS) {
        // ---- GEMM1: h0 = fp8(X @ W1). BM=128,BN=128,BK=64; 8 waves 2Mx4N 64x32 ----
        __shared__ __align__(16) float Xs[128 * 64];            // 32 KB, f32, swizzled
        __shared__ __align__(16) unsigned short Bs[128 * 64];   // 16 KB, bf16, swizzled
        const int t = threadIdx.x;
        const int lane = t & 63;
        const int wave = t >> 6;
        const int wr = wave >> 2;          // rows wr*64..+63
        const int wc = wave & 3;           // cols wc*32..+31
        const int c = lane & 15, g = lane >> 4;
        const int m0 = blockIdx.x * 128;

        f32x4 acc[4][2];
        #pragma unroll
        for (int mt = 0; mt < 4; mt++)
            #pragma unroll
            for (int nt = 0; nt < 2; nt++) acc[mt][nt] = (f32x4){0.f, 0.f, 0.f, 0.f};

        // Xs: 2048 16B-chunks (4/thread). chunk cc: row=cc>>4, slot=cc&15 holds
        // global col-seg (slot^(row&15)). Bs: 1024 chunks (2/thread), 8 slots/row.
        #define G1_ISSUE(kt)                                                             \
            _Pragma("unroll")                                                            \
            for (int s4 = 0; s4 < 4; s4++) {                                             \
                int cc = s4 * 512 + t;                                                   \
                int xrow = cc >> 4;                                                      \
                int xcs = (cc & 15) ^ (xrow & 15);                                       \
                int grow = m0 + xrow; grow = (grow < N_NODES) ? grow : (N_NODES - 1);    \
                gload_lds16(&X[(size_t)grow * IN_DIM + (kt) * 64 + xcs * 4],             \
                            (char*)Xs + s4 * 8192 + wave * 1024);                        \
            }                                                                            \
            _Pragma("unroll")                                                            \
            for (int s4 = 0; s4 < 2; s4++) {                                             \
                int cc = s4 * 512 + t;                                                   \
                int bcol = cc >> 3;                                                      \
                int bcs = (cc & 7) ^ (bcol & 7);                                         \
                gload_lds16(&Wt[(size_t)bcol * IN_DIM + (kt) * 64 + bcs * 8],            \
                            (char*)Bs + s4 * 8192 + wave * 1024);                        \
            }

        G1_ISSUE(0)
        for (int kt = 0; kt < 8; kt++) {
            __syncthreads();     // vmcnt drain: tile kt resident in LDS
            #pragma unroll
            for (int ks = 0; ks < 2; ks++) {
                bf16x8 bfr[2];
                #pragma unroll
                for (int nt = 0; nt < 2; nt++) {
                    int col = wc * 32 + nt * 16 + c;
                    int slot = (ks * 4 + g) ^ (col & 7);
                    bfr[nt] = *(const bf16x8*)&Bs[col * 64 + slot * 8];
                }
                #pragma unroll
                for (int mt = 0; mt < 4; mt++) {
                    int r = wr * 64 + mt * 16 + c;
                    int q = ks * 8 + g * 2;
                    f32x4 a0 = *(const f32x4*)&Xs[r * 64 + ((q ^ (r & 15)) * 4)];
                    f32x4 a1 = *(const f32x4*)&Xs[r * 64 + (((q + 1) ^ (r & 15)) * 4)];
                    bf16x8 af;
                    af[0] = (__bf16)a0[0]; af[1] = (__bf16)a0[1];
                    af[2] = (__bf16)a0[2]; af[3] = (__bf16)a0[3];
                    af[4] = (__bf16)a1[0]; af[5] = (__bf16)a1[1];
                    af[6] = (__bf16)a1[2]; af[7] = (__bf16)a1[3];
                    #pragma unroll
                    for (int nt = 0; nt < 2; nt++)
                        acc[mt][nt] = __builtin_amdgcn_mfma_f32_16x16x32_bf16(af, bfr[nt],
                                                                              acc[mt][nt], 0, 0, 0);
                }
            }
            __syncthreads();     // all LDS reads of tile kt done
            if (kt < 7) G1_ISSUE(kt + 1)   // async loads fly while other blocks compute
        }
        #undef G1_ISSUE

        #pragma unroll
        for (int mt = 0; mt < 4; mt++) {
            #pragma unroll
            for (int r = 0; r < 4; r++) {
                int row = m0 + wr * 64 + mt * 16 + g * 4 + r;
                if (row < N_NODES) {
                    #pragma unroll
                    for (int nt = 0; nt < 2; nt++) {
                        int col = wc * 32 + nt * 16 + c;
                        h0[(size_t)row * HID_DIM + col] = f2fp8(acc[mt][nt][r]);
                    }
                }
            }
        }
    } else {
        // ---- single-pass scatter: 8192 edges/block, 16 per thread ----
        __shared__ int cbase[NB];
        const int sb = blockIdx.x - MG_GEMM_BLOCKS;
        const int t = threadIdx.x;
        for (int b = t; b < NB; b += 512)
            cbase[b] = blk_hist_T[(size_t)b * SC_BLOCKS + sb];
        __syncthreads();
        const int eb = sb * SC_EDGES + t * 16;
        #pragma unroll
        for (int q = 0; q < 4; q++) {
            int e0 = eb + q * 4;
            if (e0 + 4 <= N_EDGES) {
                int4 s4 = *(const int4*)&src[e0];
                int4 d4 = *(const int4*)&dst[e0];
                float4 v4 = *(const float4*)&val[e0];
                #pragma unroll
                for (int k = 0; k < 4; k++) {
                    int ss = (k == 0) ? s4.x : (k == 1) ? s4.y : (k == 2) ? s4.z : s4.w;
                    int dd = (k == 0) ? d4.x : (k == 1) ? d4.y : (k == 2) ? d4.z : d4.w;
                    float vv = (k == 0) ? v4.x : (k == 1) ? v4.y : (k == 2) ? v4.z : v4.w;
                    int b = dd >> BKT_SHIFT, dl = dd & (BKT_NODES - 1);
                    int pos = atomicAdd(&cbase[b], 1);
                    int2 pr;
                    pr.x = ss | (dl << 16);
                    pr.y = __float_as_int(vv);
                    pairs_bkt[pos] = pr;
                }
            } else {
                for (int k = 0; k < 4; k++) {
                    int e = e0 + k;
                    if (e < N_EDGES) {
                        int dd = dst[e];
                        int b = dd >> BKT_SHIFT, dl = dd & (BKT_NODES - 1);
                        int pos = atomicAdd(&cbase[b], 1);
                        int2 pr;
                        pr.x = src[e] | (dl << 16);
                        pr.y = __float_as_int(val[e]);
                        pairs_bkt[pos] = pr;
                    }
                }
            }
        }
    }
}

// Fused node-level CSR: hist by dst-local -> scan -> row_ptr -> permute via LDS stage.
__global__ __launch_bounds__(512) void node_sort_fused_kernel(const int2* __restrict__ pairs_bkt,
                                                              const int* __restrict__ bucket_ptr,
                                                              int* __restrict__ row_ptr,
                                                              int2* __restrict__ pairs) {
    __shared__ int cnt[BKT_NODES];
    __shared__ int base[BKT_NODES];
    __shared__ int2 stage[NS_CAP];    // 20 KB
    const int t = threadIdx.x;
    const int b = blockIdx.x;
    const int s = bucket_ptr[b], e = bucket_ptr[b + 1];
    if (t < BKT_NODES) cnt[t] = 0;
    __syncthreads();
    for (int i = s + t; i < e; i += 512)
        atomicAdd(&cnt[pairs_bkt[i].x >> 16], 1);
    __syncthreads();
    if (t < BKT_NODES) {
        int v = cnt[t];
        int incl = wave_incl_scan(v);       // wave 0, lanes 0..63
        base[t] = s + incl - v;
    }
    __syncthreads();
    if (t < BKT_NODES) {
        int n = b * BKT_NODES + t;
        if (n < N_NODES) row_ptr[n] = base[t];
        cnt[t] = 0;
    }
    if (b == NB - 1 && t == 0) row_ptr[N_NODES] = N_EDGES;
    __syncthreads();
    for (int i = s + t; i < e; i += 512) {
        int2 pr = pairs_bkt[i];
        int dl = pr.x >> 16;
        int p = base[dl] + atomicAdd(&cnt[dl], 1);
        int loc = p - s;
        if (loc < NS_CAP) stage[loc] = pr;   // random LDS write
        else pairs[p] = pr;                  // overflow fallback (statistically never)
    }
    __syncthreads();
    const int lim = min(e - s, NS_CAP);
    for (int j = t; j < lim; j += 512)       // coalesced global write
        pairs[s + j] = stage[j];
}

// ================= compute =================

// Fused SpMM1 + ReLU + GEMM2: one wave per dst node gathers/aggregates (f32),
// stages h rows in LDS, then block computes the 4x16 h2 tile.
__global__ __launch_bounds__(256) void spmm1_fused_kernel(const unsigned char* __restrict__ h0,
                                                          const int* __restrict__ row_ptr,
                                                          const int2* __restrict__ pairs,
                                                          const float* __restrict__ W2,
                                                          unsigned short* __restrict__ h2) {
    __shared__ float W2s[HID_DIM][OUT_DIM];   // 8 KB
    __shared__ float h_lds[4][HID_DIM];       // 2 KB
    const int t = threadIdx.x;
    #pragma unroll
    for (int p = 0; p < 8; p++) {             // stage W2 (2048 floats)
        int idx = p * 256 + t;
        W2s[idx >> 4][idx & 15] = W2[idx];
    }

    const int wid = __builtin_amdgcn_readfirstlane(t >> 6);
    const int n = blockIdx.x * 4 + wid;            // wave-uniform; 50000 % 4 == 0
    const int lane = t & 63;
    const int s = row_ptr[n], e = row_ptr[n + 1];  // scalar loads
    const unsigned char* h0l = h0 + lane * 2;      // lane owns dims 2*lane, 2*lane+1
    float ax = 0.f, ay = 0.f;
    for (int base = s; base < e; base += 8) {
        float vv[8];
        const unsigned char* rp[8];
        #pragma unroll
        for (int k = 0; k < 8; k++) {
            int idx = base + k;
            int cidx = (idx < e) ? idx : (e - 1);     // scalar select; e-1 >= s valid
            int2 pr = pairs[cidx];
            vv[k] = (idx < e) ? __int_as_float(pr.y) : 0.f;
            rp[k] = h0l + (size_t)(pr.x & 0xFFFF) * HID_DIM;
        }
        unsigned short gg[8];
        #pragma unroll
        for (int k = 0; k < 8; k++) gg[k] = *(const unsigned short*)rp[k];
        #pragma unroll
        for (int k = 0; k < 8; k++) {
            f32x2 f = __builtin_amdgcn_cvt_pk_f32_fp8((int)gg[k], false);
            ax += vv[k] * f.x;
            ay += vv[k] * f.y;
        }
    }
    f32x2 hw;
    hw.x = fmaxf(ax, 0.f);
    hw.y = fmaxf(ay, 0.f);
    *(f32x2*)&h_lds[wid][lane * 2] = hw;           // stride-8B: free 2-way
    __syncthreads();

    // epilogue: thread (node, j, q) does a 32-chunk of dot(h_row, W2[:,j])
    const int node = t >> 6;
    const int j = (t & 63) >> 2;
    const int q = t & 3;
    const float* hr = h_lds[node];
    float p = 0.f;
    #pragma unroll
    for (int kk = 0; kk < 32; kk++) {
        int k = q * 32 + kk;
        p += hr[k] * W2s[k][j];                    // hr: broadcast; W2s: <=4-way
    }
    p += __shfl_xor(p, 1, 64);
    p += __shfl_xor(p, 2, 64);
    if (q == 0) {
        int nn = blockIdx.x * 4 + node;
        h2[(size_t)nn * OUT_DIM + j] = f2bf(p);
    }
}

// SpMM2: quarter-wave (16 lanes) per dst node, batch-8 clamped, bf16 h2 gather.
__global__ __launch_bounds__(256) void spmm2_node_kernel(const unsigned short* __restrict__ h2,
                                                         const int* __restrict__ row_ptr,
                                                         const int2* __restrict__ pairs,
                                                         float* __restrict__ out) {
    const int idx = blockIdx.x * 256 + threadIdx.x;
    const int n = idx >> 4;
    const int d = idx & 15;
    if (n >= N_NODES) return;
    const int s = row_ptr[n], e = row_ptr[n + 1];
    float acc = 0.f;
    for (int base = s; base < e; base += 8) {
        float vv[8];
        const unsigned short* gp[8];
        #pragma unroll
        for (int k = 0; k < 8; k++) {
            int i = base + k;
            int ci = (i < e) ? i : (e - 1);
            int2 pr = pairs[ci];
            vv[k] = (i < e) ? __int_as_float(pr.y) : 0.f;
            gp[k] = h2 + (size_t)(pr.x & 0xFFFF) * OUT_DIM + d;
        }
        unsigned short gg[8];
        #pragma unroll
        for (int k = 0; k < 8; k++) gg[k] = *gp[k];
        #pragma unroll
        for (int k = 0; k < 8; k++) acc += vv[k] * bf2f(gg[k]);
    }
    out[(size_t)n * OUT_DIM + d] = acc;
}

// ================= launch =================

extern "C" void kernel_launch(void* const* d_in, const int* in_sizes, int n_in,
                              void* d_out, int out_size, void* d_ws, size_t ws_size,
                              hipStream_t stream) {
    const float* feature   = (const float*)d_in[0];
    const int*   edge_src  = (const int*)d_in[1];
    const int*   edge_dst  = (const int*)d_in[2];
    const float* edge_vals = (const float*)d_in[3];
    const float* W1        = (const float*)d_in[4];
    const float* W2        = (const float*)d_in[5];
    float* out = (float*)d_out;

    char* ws = (char*)d_ws;
    size_t off = 0;
    auto alloc = [&](size_t bytes) {
        void* p = ws + off;
        off += (bytes + 255) & ~(size_t)255;
        return p;
    };
    unsigned char*  h0    = (unsigned char*)alloc((size_t)N_NODES * HID_DIM);
    unsigned short* Wt    = (unsigned short*)alloc((size_t)IN_DIM * HID_DIM * 2);
    unsigned short* h2    = (unsigned short*)alloc((size_t)N_NODES * OUT_DIM * 2);
    int*   bcnt           = (int*)alloc((size_t)NB * 4);
    int*   bucket_ptr     = (int*)alloc((size_t)(NB + 1) * 4);
    int*   blk_hist_T     = (int*)alloc((size_t)NB * SC_BLOCKS * 4);
    int*   row_ptr        = (int*)alloc((size_t)(N_NODES + 1) * 4);
    int2*  pairs_bkt      = (int2*)alloc((size_t)N_EDGES * 8);
    int2*  pairs          = (int2*)alloc((size_t)N_EDGES * 8);

    zero_bcnt_kernel<<<1, 1024, 0, stream>>>(bcnt);
    hist_prep_kernel<<<SC_BLOCKS + PREP_BLOCKS, 1024, 0, stream>>>(edge_dst, bcnt, blk_hist_T,
                                                                   W1, Wt);
    bucket_scan_kernel<<<1, 1024, 0, stream>>>(bcnt, bucket_ptr);
    base_scan_kernel<<<(NB + 7) / 8, 512, 0, stream>>>(bucket_ptr, blk_hist_T);
    scatter_gemm1_kernel<<<MG_GEMM_BLOCKS + SC_BLOCKS, 512, 0, stream>>>(
        feature, Wt, h0, edge_src, edge_dst, edge_vals, blk_hist_T, pairs_bkt);
    node_sort_fused_kernel<<<NB, 512, 0, stream>>>(pairs_bkt, bucket_ptr, row_ptr, pairs);

    spmm1_fused_kernel<<<(N_NODES + 3) / 4, 256, 0, stream>>>(h0, row_ptr, pairs, W2, h2);
    spmm2_node_kernel<<<(N_NODES * 16 + 255) / 256, 256, 0, stream>>>(h2, row_ptr, pairs, out);
}

// Round 25
// 134.042 us; speedup vs baseline: 1.0115x; 1.0115x over previous
//
#include <hip/hip_runtime.h>

#define N_NODES 50000
#define N_EDGES 1600000
#define IN_DIM 512
#define HID_DIM 128
#define OUT_DIM 16

#define BKT_SHIFT 6
#define BKT_NODES 64
#define NB ((N_NODES + BKT_NODES - 1) / BKT_NODES)   // 782 buckets
#define SC_EDGES 8192
#define SC_BLOCKS ((N_EDGES + SC_EDGES - 1) / SC_EDGES)   // 196 hist/scatter blocks
#define PREP_BLOCKS ((IN_DIM * HID_DIM + 1023) / 1024)    // 64
#define NS_CAP 2560                                  // node_sort LDS stage capacity
#define MG_GEMM_BLOCKS ((N_NODES + 127) / 128)       // 391 gemm1 tiles

typedef __attribute__((ext_vector_type(8))) __bf16 bf16x8;
typedef __attribute__((ext_vector_type(4))) __bf16 bf16x4;
typedef __attribute__((ext_vector_type(8))) unsigned short ushort8;
typedef __attribute__((ext_vector_type(4))) float f32x4;
typedef __attribute__((ext_vector_type(2))) float f32x2;

static __device__ __forceinline__ unsigned short f2bf(float x) {
    unsigned int u = __float_as_uint(x);
    u += 0x7FFFu + ((u >> 16) & 1u);   // round-to-nearest-even
    return (unsigned short)(u >> 16);
}
static __device__ __forceinline__ float bf2f(unsigned short v) {
    return __uint_as_float(((unsigned int)v) << 16);
}
static __device__ __forceinline__ unsigned char f2fp8(float x) {
    int pk = __builtin_amdgcn_cvt_pk_fp8_f32(x, x, 0, false);   // HW e4m3 (gfx950 OCP)
    return (unsigned char)(pk & 0xFF);
}

__device__ inline int wave_incl_scan(int v) {
    #pragma unroll
    for (int off = 1; off < 64; off <<= 1) {
        int x = __shfl_up(v, off, 64);
        if ((threadIdx.x & 63) >= off) v += x;
    }
    return v;
}

// ================= CSR build =================

__global__ void zero_bcnt_kernel(int* __restrict__ bcnt) {
    int t = threadIdx.x;
    if (t < NB) bcnt[t] = 0;
}

// blocks [0,196): bucket hist (8192 edges, int4-vectorized) + per-block counts to
// blk_hist_T[bucket][block]. blocks [196,260): prep Wt.
__global__ __launch_bounds__(1024) void hist_prep_kernel(const int* __restrict__ dst,
                                                         int* __restrict__ bcnt,
                                                         int* __restrict__ blk_hist_T,
                                                         const float* __restrict__ W1,
                                                         unsigned short* __restrict__ Wt) {
    if (blockIdx.x >= SC_BLOCKS) {
        int i = (blockIdx.x - SC_BLOCKS) * 1024 + threadIdx.x;
        if (i < IN_DIM * HID_DIM) {
            int k = i >> 7, col = i & 127;
            Wt[(size_t)col * IN_DIM + k] = f2bf(W1[i]);
        }
        return;
    }
    __shared__ int lc[NB];
    const int t = threadIdx.x;
    for (int b = t; b < NB; b += 1024) lc[b] = 0;
    __syncthreads();
    const int eb = blockIdx.x * SC_EDGES + t * 8;
    #pragma unroll
    for (int q = 0; q < 2; q++) {
        int e0 = eb + q * 4;
        if (e0 + 4 <= N_EDGES) {
            int4 d4 = *(const int4*)&dst[e0];
            atomicAdd(&lc[d4.x >> BKT_SHIFT], 1);
            atomicAdd(&lc[d4.y >> BKT_SHIFT], 1);
            atomicAdd(&lc[d4.z >> BKT_SHIFT], 1);
            atomicAdd(&lc[d4.w >> BKT_SHIFT], 1);
        } else {
            for (int k = 0; k < 4; k++) {
                int e = e0 + k;
                if (e < N_EDGES) atomicAdd(&lc[dst[e] >> BKT_SHIFT], 1);
            }
        }
    }
    __syncthreads();
    for (int b = t; b < NB; b += 1024) {
        int c = lc[b];
        blk_hist_T[(size_t)b * SC_BLOCKS + blockIdx.x] = c;
        if (c) atomicAdd(&bcnt[b], c);
    }
}

__global__ __launch_bounds__(1024) void bucket_scan_kernel(const int* __restrict__ bcnt,
                                                           int* __restrict__ bucket_ptr) {
    __shared__ int wsums[16];
    const int t = threadIdx.x;
    const int lane = t & 63, wid = t >> 6;
    int v = (t < NB) ? bcnt[t] : 0;
    int incl = wave_incl_scan(v);
    if (lane == 63) wsums[wid] = incl;
    __syncthreads();
    if (wid == 0) {
        int wv = (lane < 16) ? wsums[lane] : 0;
        int ws = wave_incl_scan(wv);
        if (lane < 16) wsums[lane] = ws;
    }
    __syncthreads();
    int woff = wid ? wsums[wid - 1] : 0;
    int excl = woff + incl - v;
    if (t < NB) bucket_ptr[t] = excl;
    if (t == NB - 1) bucket_ptr[NB] = excl + v;
}

// One wave per bucket: in-place exclusive-scan blk_hist_T rows (coalesced).
__global__ __launch_bounds__(512) void base_scan_kernel(const int* __restrict__ bucket_ptr,
                                                        int* __restrict__ blk_hist_T) {
    const int lane = threadIdx.x & 63;
    const int b = blockIdx.x * 8 + (threadIdx.x >> 6);
    if (b >= NB) return;
    int* row = blk_hist_T + (size_t)b * SC_BLOCKS;
    int carry = bucket_ptr[b];
    for (int c0 = 0; c0 < SC_BLOCKS; c0 += 64) {
        int idx = c0 + lane;
        int v = (idx < SC_BLOCKS) ? row[idx] : 0;
        int incl = wave_incl_scan(v);
        if (idx < SC_BLOCKS) row[idx] = carry + incl - v;
        carry += __shfl(incl, 63, 64);
    }
}

// ======= merged: blocks [0,391) gemm1 (BK=64, 2-deep reg pipeline); [391,587) scatter =======

#define G1_XSTR 72
#define G1_BSTR 72
__global__ __launch_bounds__(512) void scatter_gemm1_kernel(const float* __restrict__ X,
                                                            const unsigned short* __restrict__ Wt,
                                                            unsigned char* __restrict__ h0,
                                                            const int* __restrict__ src,
                                                            const int* __restrict__ dst,
                                                            const float* __restrict__ val,
                                                            const int* __restrict__ blk_hist_T,
                                                            int2* __restrict__ pairs_bkt) {
    if (blockIdx.x < MG_GEMM_BLOCKS) {
        // ---- GEMM1: h0 = fp8(X @ W1). BM=128,BN=128,BK=64; 8 waves 2Mx4N 64x32 ----
        __shared__ __align__(16) unsigned short Xs[128 * G1_XSTR];   // 18432 B
        __shared__ __align__(16) unsigned short Bs[128 * G1_BSTR];   // 18432 B
        const int t = threadIdx.x;
        const int lane = t & 63;
        const int wave = t >> 6;
        const int wr = wave >> 2;          // rows wr*64..+63
        const int wc = wave & 3;           // cols wc*32..+31
        const int c = lane & 15, g = lane >> 4;
        const int m0 = blockIdx.x * 128;

        f32x4 acc[4][2];
        #pragma unroll
        for (int mt = 0; mt < 4; mt++)
            #pragma unroll
            for (int nt = 0; nt < 2; nt++) acc[mt][nt] = (f32x4){0.f, 0.f, 0.f, 0.f};

        float4 xrA[4], xrB[4];
        ushort8 brA[2], brB[2];

        #define G1_LOAD(XR, BR, kt)                                                          \
            _Pragma("unroll")                                                                \
            for (int p = 0; p < 4; p++) {                                                    \
                int idx = p * 512 + t;                                                       \
                int xrow = idx >> 4, xseg = idx & 15;                                        \
                int grow = m0 + xrow; grow = (grow < N_NODES) ? grow : (N_NODES - 1);        \
                XR[p] = *(const float4*)&X[(size_t)grow * IN_DIM + (kt) * 64 + xseg * 4];    \
            }                                                                                \
            _Pragma("unroll")                                                                \
            for (int p = 0; p < 2; p++) {                                                    \
                int idx = p * 512 + t;                                                       \
                int bcol = idx >> 3, bseg = idx & 7;                                         \
                BR[p] = *(const ushort8*)&Wt[(size_t)bcol * IN_DIM + (kt) * 64 + bseg * 8];  \
            }

        #define G1_WRITE(XR, BR)                                                             \
            _Pragma("unroll")                                                                \
            for (int p = 0; p < 4; p++) {                                                    \
                int idx = p * 512 + t;                                                       \
                int xrow = idx >> 4, xseg = idx & 15;                                        \
                bf16x4 xw;                                                                   \
                xw[0] = (__bf16)XR[p].x; xw[1] = (__bf16)XR[p].y;                            \
                xw[2] = (__bf16)XR[p].z; xw[3] = (__bf16)XR[p].w;                            \
                *(bf16x4*)&Xs[xrow * G1_XSTR + xseg * 4] = xw;                               \
            }                                                                                \
            _Pragma("unroll")                                                                \
            for (int p = 0; p < 2; p++) {                                                    \
                int idx = p * 512 + t;                                                       \
                int bcol = idx >> 3, bseg = idx & 7;                                         \
                *(ushort8*)&Bs[bcol * G1_BSTR + bseg * 8] = BR[p];                           \
            }

        G1_LOAD(xrA, brA, 0)
        G1_LOAD(xrB, brB, 1)      // 2 k-tiles (12 loads/thread) in flight
        #pragma unroll
        for (int kt = 0; kt < 8; kt++) {
            if (kt & 1) { G1_WRITE(xrB, brB) } else { G1_WRITE(xrA, brA) }
            __syncthreads();
            if (kt + 2 < 8) {     // refill the set just drained -> stays 2-deep
                if (kt & 1) { G1_LOAD(xrB, brB, kt + 2) } else { G1_LOAD(xrA, brA, kt + 2) }
            }
            #pragma unroll
            for (int ks = 0; ks < 2; ks++) {
                bf16x8 bf[2];
                #pragma unroll
                for (int nt = 0; nt < 2; nt++) {
                    int col = wc * 32 + nt * 16 + c;
                    bf[nt] = *(const bf16x8*)&Bs[col * G1_BSTR + ks * 32 + g * 8];
                }
                #pragma unroll
                for (int mt = 0; mt < 4; mt++) {
                    bf16x8 af = *(const bf16x8*)&Xs[(wr * 64 + mt * 16 + c) * G1_XSTR + ks * 32 + g * 8];
                    #pragma unroll
                    for (int nt = 0; nt < 2; nt++)
                        acc[mt][nt] = __builtin_amdgcn_mfma_f32_16x16x32_bf16(af, bf[nt],
                                                                              acc[mt][nt], 0, 0, 0);
                }
            }
            __syncthreads();
        }
        #undef G1_LOAD
        #undef G1_WRITE

        #pragma unroll
        for (int mt = 0; mt < 4; mt++) {
            #pragma unroll
            for (int r = 0; r < 4; r++) {
                int row = m0 + wr * 64 + mt * 16 + g * 4 + r;
                if (row < N_NODES) {
                    #pragma unroll
                    for (int nt = 0; nt < 2; nt++) {
                        int col = wc * 32 + nt * 16 + c;
                        h0[(size_t)row * HID_DIM + col] = f2fp8(acc[mt][nt][r]);
                    }
                }
            }
        }
    } else {
        // ---- single-pass scatter: 8192 edges/block, 16 per thread ----
        __shared__ int cbase[NB];
        const int sb = blockIdx.x - MG_GEMM_BLOCKS;
        const int t = threadIdx.x;
        for (int b = t; b < NB; b += 512)
            cbase[b] = blk_hist_T[(size_t)b * SC_BLOCKS + sb];
        __syncthreads();
        const int eb = sb * SC_EDGES + t * 16;
        #pragma unroll
        for (int q = 0; q < 4; q++) {
            int e0 = eb + q * 4;
            if (e0 + 4 <= N_EDGES) {
                int4 s4 = *(const int4*)&src[e0];
                int4 d4 = *(const int4*)&dst[e0];
                float4 v4 = *(const float4*)&val[e0];
                #pragma unroll
                for (int k = 0; k < 4; k++) {
                    int ss = (k == 0) ? s4.x : (k == 1) ? s4.y : (k == 2) ? s4.z : s4.w;
                    int dd = (k == 0) ? d4.x : (k == 1) ? d4.y : (k == 2) ? d4.z : d4.w;
                    float vv = (k == 0) ? v4.x : (k == 1) ? v4.y : (k == 2) ? v4.z : v4.w;
                    int b = dd >> BKT_SHIFT, dl = dd & (BKT_NODES - 1);
                    int pos = atomicAdd(&cbase[b], 1);
                    int2 pr;
                    pr.x = ss | (dl << 16);
                    pr.y = __float_as_int(vv);
                    pairs_bkt[pos] = pr;
                }
            } else {
                for (int k = 0; k < 4; k++) {
                    int e = e0 + k;
                    if (e < N_EDGES) {
                        int dd = dst[e];
                        int b = dd >> BKT_SHIFT, dl = dd & (BKT_NODES - 1);
                        int pos = atomicAdd(&cbase[b], 1);
                        int2 pr;
                        pr.x = src[e] | (dl << 16);
                        pr.y = __float_as_int(val[e]);
                        pairs_bkt[pos] = pr;
                    }
                }
            }
        }
    }
}

// Fused node-level CSR: hist by dst-local -> scan -> row_ptr -> permute via LDS stage.
__global__ __launch_bounds__(512) void node_sort_fused_kernel(const int2* __restrict__ pairs_bkt,
                                                              const int* __restrict__ bucket_ptr,
                                                              int* __restrict__ row_ptr,
                                                              int2* __restrict__ pairs) {
    __shared__ int cnt[BKT_NODES];
    __shared__ int base[BKT_NODES];
    __shared__ int2 stage[NS_CAP];    // 20 KB
    const int t = threadIdx.x;
    const int b = blockIdx.x;
    const int s = bucket_ptr[b], e = bucket_ptr[b + 1];
    if (t < BKT_NODES) cnt[t] = 0;
    __syncthreads();
    for (int i = s + t; i < e; i += 512)
        atomicAdd(&cnt[pairs_bkt[i].x >> 16], 1);
    __syncthreads();
    if (t < BKT_NODES) {
        int v = cnt[t];
        int incl = wave_incl_scan(v);       // wave 0, lanes 0..63
        base[t] = s + incl - v;
    }
    __syncthreads();
    if (t < BKT_NODES) {
        int n = b * BKT_NODES + t;
        if (n < N_NODES) row_ptr[n] = base[t];
        cnt[t] = 0;
    }
    if (b == NB - 1 && t == 0) row_ptr[N_NODES] = N_EDGES;
    __syncthreads();
    for (int i = s + t; i < e; i += 512) {
        int2 pr = pairs_bkt[i];
        int dl = pr.x >> 16;
        int p = base[dl] + atomicAdd(&cnt[dl], 1);
        int loc = p - s;
        if (loc < NS_CAP) stage[loc] = pr;   // random LDS write
        else pairs[p] = pr;                  // overflow fallback (statistically never)
    }
    __syncthreads();
    const int lim = min(e - s, NS_CAP);
    for (int j = t; j < lim; j += 512)       // coalesced global write
        pairs[s + j] = stage[j];
}

// ================= compute =================

// Fused SpMM1 + ReLU + GEMM2: one wave per dst node gathers/aggregates (f32),
// stages h rows in LDS, then block computes the 4x16 h2 tile.
__global__ __launch_bounds__(256) void spmm1_fused_kernel(const unsigned char* __restrict__ h0,
                                                          const int* __restrict__ row_ptr,
                                                          const int2* __restrict__ pairs,
                                                          const float* __restrict__ W2,
                                                          unsigned short* __restrict__ h2) {
    __shared__ float W2s[HID_DIM][OUT_DIM];   // 8 KB
    __shared__ float h_lds[4][HID_DIM];       // 2 KB
    const int t = threadIdx.x;
    #pragma unroll
    for (int p = 0; p < 8; p++) {             // stage W2 (2048 floats)
        int idx = p * 256 + t;
        W2s[idx >> 4][idx & 15] = W2[idx];
    }

    const int wid = __builtin_amdgcn_readfirstlane(t >> 6);
    const int n = blockIdx.x * 4 + wid;            // wave-uniform; 50000 % 4 == 0
    const int lane = t & 63;
    const int s = row_ptr[n], e = row_ptr[n + 1];  // scalar loads
    const unsigned char* h0l = h0 + lane * 2;      // lane owns dims 2*lane, 2*lane+1
    float ax = 0.f, ay = 0.f;
    for (int base = s; base < e; base += 8) {
        float vv[8];
        const unsigned char* rp[8];
        #pragma unroll
        for (int k = 0; k < 8; k++) {
            int idx = base + k;
            int cidx = (idx < e) ? idx : (e - 1);     // scalar select; e-1 >= s valid
            int2 pr = pairs[cidx];
            vv[k] = (idx < e) ? __int_as_float(pr.y) : 0.f;
            rp[k] = h0l + (size_t)(pr.x & 0xFFFF) * HID_DIM;
        }
        unsigned short gg[8];
        #pragma unroll
        for (int k = 0; k < 8; k++) gg[k] = *(const unsigned short*)rp[k];
        #pragma unroll
        for (int k = 0; k < 8; k++) {
            f32x2 f = __builtin_amdgcn_cvt_pk_f32_fp8((int)gg[k], false);
            ax += vv[k] * f.x;
            ay += vv[k] * f.y;
        }
    }
    f32x2 hw;
    hw.x = fmaxf(ax, 0.f);
    hw.y = fmaxf(ay, 0.f);
    *(f32x2*)&h_lds[wid][lane * 2] = hw;           // stride-8B: free 2-way
    __syncthreads();

    // epilogue: thread (node, j, q) does a 32-chunk of dot(h_row, W2[:,j])
    const int node = t >> 6;
    const int j = (t & 63) >> 2;
    const int q = t & 3;
    const float* hr = h_lds[node];
    float p = 0.f;
    #pragma unroll
    for (int kk = 0; kk < 32; kk++) {
        int k = q * 32 + kk;
        p += hr[k] * W2s[k][j];                    // hr: broadcast; W2s: <=4-way
    }
    p += __shfl_xor(p, 1, 64);
    p += __shfl_xor(p, 2, 64);
    if (q == 0) {
        int nn = blockIdx.x * 4 + node;
        h2[(size_t)nn * OUT_DIM + j] = f2bf(p);
    }
}

// SpMM2: quarter-wave (16 lanes) per dst node, batch-8 clamped, bf16 h2 gather.
__global__ __launch_bounds__(256) void spmm2_node_kernel(const unsigned short* __restrict__ h2,
                                                         const int* __restrict__ row_ptr,
                                                         const int2* __restrict__ pairs,
                                                         float* __restrict__ out) {
    const int idx = blockIdx.x * 256 + threadIdx.x;
    const int n = idx >> 4;
    const int d = idx & 15;
    if (n >= N_NODES) return;
    const int s = row_ptr[n], e = row_ptr[n + 1];
    float acc = 0.f;
    for (int base = s; base < e; base += 8) {
        float vv[8];
        const unsigned short* gp[8];
        #pragma unroll
        for (int k = 0; k < 8; k++) {
            int i = base + k;
            int ci = (i < e) ? i : (e - 1);
            int2 pr = pairs[ci];
            vv[k] = (i < e) ? __int_as_float(pr.y) : 0.f;
            gp[k] = h2 + (size_t)(pr.x & 0xFFFF) * OUT_DIM + d;
        }
        unsigned short gg[8];
        #pragma unroll
        for (int k = 0; k < 8; k++) gg[k] = *gp[k];
        #pragma unroll
        for (int k = 0; k < 8; k++) acc += vv[k] * bf2f(gg[k]);
    }
    out[(size_t)n * OUT_DIM + d] = acc;
}

// ================= launch =================

extern "C" void kernel_launch(void* const* d_in, const int* in_sizes, int n_in,
                              void* d_out, int out_size, void* d_ws, size_t ws_size,
                              hipStream_t stream) {
    const float* feature   = (const float*)d_in[0];
    const int*   edge_src  = (const int*)d_in[1];
    const int*   edge_dst  = (const int*)d_in[2];
    const float* edge_vals = (const float*)d_in[3];
    const float* W1        = (const float*)d_in[4];
    const float* W2        = (const float*)d_in[5];
    float* out = (float*)d_out;

    char* ws = (char*)d_ws;
    size_t off = 0;
    auto alloc = [&](size_t bytes) {
        void* p = ws + off;
        off += (bytes + 255) & ~(size_t)255;
        return p;
    };
    unsigned char*  h0    = (unsigned char*)alloc((size_t)N_NODES * HID_DIM);
    unsigned short* Wt    = (unsigned short*)alloc((size_t)IN_DIM * HID_DIM * 2);
    unsigned short* h2    = (unsigned short*)alloc((size_t)N_NODES * OUT_DIM * 2);
    int*   bcnt           = (int*)alloc((size_t)NB * 4);
    int*   bucket_ptr     = (int*)alloc((size_t)(NB + 1) * 4);
    int*   blk_hist_T     = (int*)alloc((size_t)NB * SC_BLOCKS * 4);
    int*   row_ptr        = (int*)alloc((size_t)(N_NODES + 1) * 4);
    int2*  pairs_bkt      = (int2*)alloc((size_t)N_EDGES * 8);
    int2*  pairs          = (int2*)alloc((size_t)N_EDGES * 8);

    zero_bcnt_kernel<<<1, 1024, 0, stream>>>(bcnt);
    hist_prep_kernel<<<SC_BLOCKS + PREP_BLOCKS, 1024, 0, stream>>>(edge_dst, bcnt, blk_hist_T,
                                                                   W1, Wt);
    bucket_scan_kernel<<<1, 1024, 0, stream>>>(bcnt, bucket_ptr);
    base_scan_kernel<<<(NB + 7) / 8, 512, 0, stream>>>(bucket_ptr, blk_hist_T);
    scatter_gemm1_kernel<<<MG_GEMM_BLOCKS + SC_BLOCKS, 512, 0, stream>>>(
        feature, Wt, h0, edge_src, edge_dst, edge_vals, blk_hist_T, pairs_bkt);
    node_sort_fused_kernel<<<NB, 512, 0, stream>>>(pairs_bkt, bucket_ptr, row_ptr, pairs);

    spmm1_fused_kernel<<<(N_NODES + 3) / 4, 256, 0, stream>>>(h0, row_ptr, pairs, W2, h2);
    spmm2_node_kernel<<<(N_NODES * 16 + 255) / 256, 256, 0, stream>>>(h2, row_ptr, pairs, out);
}